// Round 11
// baseline (114.591 us; speedup 1.0000x reference)
//
#include <hip/hip_runtime.h>
#include <cstdint>

typedef unsigned short u16;
typedef __attribute__((ext_vector_type(8))) __bf16 bf16x8;
typedef __attribute__((ext_vector_type(4))) float f32x4;

#define NROWS 8192
#define KDIM  256
#define BK 64

__device__ __forceinline__ u16 f2bf(float f) {
  uint32_t u = __builtin_bit_cast(uint32_t, f);
  return (u16)((u + 0x7fffu + ((u >> 16) & 1u)) >> 16);
}

// One wave per row: convert scale*row to bf16 (RNE) and sum of squares of the RAW row.
// A is prepped with scale=-2 so the GEMM directly yields acc = -2*dot (exact: *2 is
// an exponent bump in f32, then one RNE to bf16 -- same rounding as scale=1).
__global__ void __launch_bounds__(256) prep_kernel(const float* __restrict__ src,
                                                   u16* __restrict__ dst,
                                                   float* __restrict__ norms,
                                                   float scale) {
  const int row  = blockIdx.x * 4 + (threadIdx.x >> 6);
  const int lane = threadIdx.x & 63;
  const float4 v = *reinterpret_cast<const float4*>(&src[row * KDIM + lane * 4]);
  float s = v.x * v.x + v.y * v.y + v.z * v.z + v.w * v.w;
#pragma unroll
  for (int off = 32; off > 0; off >>= 1) s += __shfl_down(s, off, 64);
  ushort4 b;
  b.x = f2bf(scale * v.x); b.y = f2bf(scale * v.y);
  b.z = f2bf(scale * v.z); b.w = f2bf(scale * v.w);
  *reinterpret_cast<ushort4*>(&dst[row * KDIM + lane * 4]) = b;
  if (lane == 0) norms[row] = s;
}

// r4 skeleton (proven 89.5us: 128^2 tile, 4 waves, BK=64, __syncthreads 2-phase loop,
// swapped-operand MFMA) with three surgical changes:
//  1. LDS cell layout [chunk(8)][row(128)][8 bf16]: a frag-read's 256 dwords spread
//     evenly over all 32 banks (byte/4 % 32 = lo*4+phase covers every residue 8x);
//     the old [row][64] layout (128B rows = 32 banks) used only 16 residues -> 2x
//     LDS stall (part of r6's 12.6M SQ_LDS_BANK_CONFLICT).
//  2. PREFILL: each thread stores SENT to its 16 output float4 slots BEFORE the
//     K-loop -- the 256MB write stream drains under compute instead of after it.
//     Epilogue then stores ONLY float4 groups containing an unmasked (d2<=64)
//     element: with this data min d2 ~ 250, i.e. zero late stores. WAW-safe: the
//     K-loop's final __syncthreads drains vmcnt(0) (prefill acked) before any
//     sparse store. Deterministic: same inputs -> same mask -> same work.
//  3. Epilogue math: acc is already -2*dot (prep scale), so d2 = (x2+y2) + acc;
//     sqrt only inside the rare unmasked branch.
// SENTINEL: not -inf ((-inf)-(-inf)=NaN in harness diff) and finite under bf16 RNE
// (-FLT_MAX bf16-rounds to -inf); -3.0e38 is safe.
__global__ void __launch_bounds__(256) gemm_mask_kernel(const u16* __restrict__ A,
                                                        const u16* __restrict__ B,
                                                        const float* __restrict__ x2,
                                                        const float* __restrict__ y2,
                                                        float* __restrict__ out) {
  __shared__ __align__(16) u16 sA[128 * BK];
  __shared__ __align__(16) u16 sB[128 * BK];
  const int tid  = threadIdx.x;
  const int lane = tid & 63;
  const int wave = tid >> 6;
  const int lo = lane & 15, hi = lane >> 4;
  const int wr = wave >> 1, wc = wave & 1;
  const int bx = blockIdx.x & 63;
  const int by = blockIdx.x >> 6;
  const int rowBase = by * 128;
  const int colBase = bx * 128;

  // ---- Prefill: SENT to this thread's 16 output float4 slots (fire-and-forget).
  const float SENT = -3.0e38f;
  const f32x4 s4 = {SENT, SENT, SENT, SENT};
  float* obase = out + (size_t)(rowBase + wr * 64 + lo) * NROWS + colBase + wc * 64 + hi * 4;
#pragma unroll
  for (int m = 0; m < 4; ++m) {
    float* orow = obase + (size_t)m * 16 * NROWS;
#pragma unroll
    for (int n = 0; n < 4; ++n)
      *reinterpret_cast<f32x4*>(&orow[n * 16]) = s4;
  }

  // Staging sources: cell c = chunk*128 + row; thread stages c = tid + it*256.
  // row = c&127, chunk = c>>7; src k-offset = chunk*8, dest = smem + c*8 (linear).
  f32x4 acc[4][4] = {};

  for (int k0 = 0; k0 < KDIM; k0 += BK) {
#pragma unroll
    for (int it = 0; it < 4; ++it) {
      const int c = it * 256 + tid;
      const int r = c & 127;
      const int ch = c >> 7;
      __builtin_amdgcn_global_load_lds(
          (const __attribute__((address_space(1))) void*)&A[(size_t)(rowBase + r) * KDIM + k0 + ch * 8],
          (__attribute__((address_space(3))) void*)&sA[(size_t)c * 8], 16, 0, 0);
      __builtin_amdgcn_global_load_lds(
          (const __attribute__((address_space(1))) void*)&B[(size_t)(colBase + r) * KDIM + k0 + ch * 8],
          (__attribute__((address_space(3))) void*)&sB[(size_t)c * 8], 16, 0, 0);
    }
    __syncthreads();

#pragma unroll
    for (int kk = 0; kk < BK; kk += 32) {
      const int chBase = kk >> 3;  // chunk = kk/8 + hi
      bf16x8 af[4], bf[4];
#pragma unroll
      for (int m = 0; m < 4; ++m)
        af[m] = *reinterpret_cast<const bf16x8*>(&sA[((chBase + hi) * 128 + wr * 64 + m * 16 + lo) * 8]);
#pragma unroll
      for (int n = 0; n < 4; ++n)
        bf[n] = *reinterpret_cast<const bf16x8*>(&sB[((chBase + hi) * 128 + wc * 64 + n * 16 + lo) * 8]);
#pragma unroll
      for (int m = 0; m < 4; ++m)
#pragma unroll
        for (int n = 0; n < 4; ++n)
          acc[m][n] = __builtin_amdgcn_mfma_f32_16x16x32_bf16(bf[n], af[m], acc[m][n], 0, 0, 0);
    }
    __syncthreads();   // final iteration: drains vmcnt(0) -> prefill stores acked
  }

  // ---- Sparse epilogue: store only float4 groups with an unmasked element.
  // acc = -2*dot; d2 = x2[row] + y2[col] + acc. Unmasked iff d2 <= 64.
  float4 yv[4];
#pragma unroll
  for (int n = 0; n < 4; ++n)
    yv[n] = *reinterpret_cast<const float4*>(&y2[colBase + wc * 64 + n * 16 + hi * 4]);
#pragma unroll
  for (int m = 0; m < 4; ++m) {
    const int row  = rowBase + wr * 64 + m * 16 + lo;
    const float xr = x2[row];
    float* orow = obase + (size_t)m * 16 * NROWS;
#pragma unroll
    for (int n = 0; n < 4; ++n) {
      const float d0 = xr + yv[n].x + acc[m][n][0];
      const float d1 = xr + yv[n].y + acc[m][n][1];
      const float d2 = xr + yv[n].z + acc[m][n][2];
      const float d3 = xr + yv[n].w + acc[m][n][3];
      if (d0 <= 64.0f || d1 <= 64.0f || d2 <= 64.0f || d3 <= 64.0f) {
        f32x4 o;
        o[0] = (d0 <= 64.0f) ? -__builtin_sqrtf(fmaxf(d0, 0.0f)) : SENT;
        o[1] = (d1 <= 64.0f) ? -__builtin_sqrtf(fmaxf(d1, 0.0f)) : SENT;
        o[2] = (d2 <= 64.0f) ? -__builtin_sqrtf(fmaxf(d2, 0.0f)) : SENT;
        o[3] = (d3 <= 64.0f) ? -__builtin_sqrtf(fmaxf(d3, 0.0f)) : SENT;
        *reinterpret_cast<f32x4*>(&orow[n * 16]) = o;
      }
    }
  }
}

extern "C" void kernel_launch(void* const* d_in, const int* in_sizes, int n_in,
                              void* d_out, int out_size, void* d_ws, size_t ws_size,
                              hipStream_t stream) {
  const float* x  = (const float*)d_in[0];
  const float* xn = (const float*)d_in[1];
  float* out = (float*)d_out;

  // Workspace: bf16 -2X (4MB) | bf16 Xn (4MB) | x2 (32KB) | y2 (32KB)
  u16* Xb = (u16*)d_ws;
  u16* Yb = Xb + (size_t)NROWS * KDIM;
  float* x2 = (float*)(Yb + (size_t)NROWS * KDIM);
  float* y2 = x2 + NROWS;

  prep_kernel<<<NROWS / 4, 256, 0, stream>>>(x, Xb, x2, -2.0f);
  prep_kernel<<<NROWS / 4, 256, 0, stream>>>(xn, Yb, y2, 1.0f);
  gemm_mask_kernel<<<dim3(64 * 64), dim3(256), 0, stream>>>(Xb, Yb, x2, y2, out);
}